// Round 7
// baseline (25.852 us; speedup 1.0000x reference)
//
#include <hip/hip_runtime.h>
#include <math.h>

#define SZ 256
#define KPTS 64
#define GROUPS 4
#define SEGS_PER (KPTS / GROUPS)   // 16 segments per thread
#define NBLK (4 * SZ * GROUPS)     // 4096 prod blocks
#define K_SIGN 100000.0f
#define EPS_C 1e-5f
#define INV_2PI 0.15915494309189535f
#define PI_F 3.14159265358979323846f
// 2*K_SIGN*log2(e): tanh(2K*c) = 1 - 2/(exp2(K2_LOG2E*c)+1)
#define K2_LOG2E 288539.00817779269f
// |cross| above this => |tanh - sign| < 2^-31, use hard sign
#define CROSS_BAND 1.1091e-4f

__device__ __forceinline__ float fast_rcp(float x)  { return __builtin_amdgcn_rcpf(x); }
__device__ __forceinline__ float fast_sqrt(float x) { return __builtin_amdgcn_sqrtf(x); }
__device__ __forceinline__ float fast_rsq(float x)  { return __builtin_amdgcn_rsqf(x); }
__device__ __forceinline__ float fast_exp2(float x) { return __builtin_amdgcn_exp2f(x); }

// acos approx (Abramowitz-Stegun 4.4.45), max err ~6.7e-5 rad.
__device__ __forceinline__ float fast_acos(float x) {
    float ax = fabsf(x);
    float s  = fast_sqrt(1.0f - ax);
    float p  = s * fmaf(ax, fmaf(ax, fmaf(ax, -0.0187292994f, 0.0742610037f),
                                  -0.2121143937f), 1.5707288f);
    return (x >= 0.0f) ? p : (PI_F - p);
}

// d_ws: ws[blk] = per-block max, blk in [0,4096); fully rewritten every call.

// grid = bn(4) * i(256) * jq(4) = 4096 blocks, block = 256 threads.
// thread t: g = t&3 (16-segment group), jloc = t>>2 -> pixel j = jq*64+jloc.
__global__ __launch_bounds__(256) void contour_prod_kernel(
    const float* __restrict__ contour,   // [4][64][2]
    float* __restrict__ out,             // [4][256][256] unnormalized
    float* __restrict__ ws)              // [4096] per-block maxes
{
    __shared__ float cx[KPTS + 1];
    __shared__ float cy[KPTS + 1];
    __shared__ float wred[4];

    const int blk = blockIdx.x;
    const int jq  = blk & 3;
    const int i   = (blk >> 2) & 255;
    const int bn  = blk >> 10;

    const int t = threadIdx.x;
    if (t < KPTS) {
        float x = contour[(bn * KPTS + t) * 2 + 0];
        float y = contour[(bn * KPTS + t) * 2 + 1];
        cx[t] = x; cy[t] = y;
        if (t == 0) { cx[KPTS] = x; cy[KPTS] = y; }   // wraparound dup
    }
    __syncthreads();

    const int g    = t & 3;
    const int jloc = t >> 2;
    const int j    = (jq << 6) + jloc;

    const float mx = (float)i * (1.0f / (float)SZ);
    const float my = (float)j * (1.0f / (float)SZ);

    const int base = g * SEGS_PER;

    float dxc   = cx[base] - mx;
    float dyc   = cy[base] - my;
    float n2c   = fmaf(dxc, dxc, dyc * dyc);
    float minn2 = n2c;                  // min of squared norms; sqrt at the end
    float acc   = 0.0f;

    #pragma unroll
    for (int kk = 0; kk < SEGS_PER; ++kk) {
        const float dxn = cx[base + kk + 1] - mx;
        const float dyn = cy[base + kk + 1] - my;
        const float n2n = fmaf(dxn, dxn, dyn * dyn);
        minn2 = fminf(minn2, n2n);

        const float cross = dyc * dxn - dxc * dyn;
        const float dot   = fmaf(dxc, dxn, dyc * dyn);

        float cosang = dot * fast_rsq(n2c * n2n);
        cosang = fminf(fmaxf(cosang, -1.0f + EPS_C), 1.0f - EPS_C);  // v_med3
        const float ang = fast_acos(cosang);

        // hard sign (exact to 2^-31 outside the band), smooth tanh when any
        // lane of the wave is inside the band (wave-uniform branch).
        float sa = copysignf(ang, cross);
        if (__any(fabsf(cross) < CROSS_BAND)) {
            const float tt    = fast_exp2(K2_LOG2E * cross);
            const float tanhv = fmaf(-2.0f, fast_rcp(tt + 1.0f), 1.0f);
            sa = tanhv * ang;           // exact reference formula, all lanes
        }
        acc += sa;

        dxc = dxn; dyc = dyn; n2c = n2n;
    }

    // combine 4 segment-groups of the pixel
    acc += __shfl_xor(acc, 1, 64);
    acc += __shfl_xor(acc, 2, 64);
    minn2 = fminf(minn2, __shfl_xor(minn2, 1, 64));
    minn2 = fminf(minn2, __shfl_xor(minn2, 2, 64));

    const float prod = fabsf(acc) * INV_2PI * fast_sqrt(minn2);
    if (g == 0)
        out[((bn << 8) + i) * SZ + j] = prod;

    // block max -> plain store
    float wmax = prod;
    #pragma unroll
    for (int off = 32; off > 0; off >>= 1)
        wmax = fmaxf(wmax, __shfl_down(wmax, off, 64));
    if ((t & 63) == 0) wred[t >> 6] = wmax;
    __syncthreads();
    if (t == 0)
        ws[blk] = fmaxf(fmaxf(wred[0], wred[1]), fmaxf(wred[2], wred[3]));
}

// 256 blocks x 256 threads. Each block re-reduces ws[0..4095] (L2-hit, 16 KB),
// then normalizes its 1024-pixel chunk (float4 per thread).
__global__ __launch_bounds__(256) void contour_norm_kernel(
    float4* __restrict__ out,
    const float* __restrict__ ws)
{
    __shared__ float wred[4];
    __shared__ float smax;

    const int t = threadIdx.x;
    const float4* w4 = (const float4*)ws;   // 1024 float4

    float m = 0.0f;                          // prod >= 0
    #pragma unroll
    for (int r = 0; r < 4; ++r) {
        float4 v = w4[t + (r << 8)];
        m = fmaxf(m, fmaxf(fmaxf(v.x, v.y), fmaxf(v.z, v.w)));
    }
    #pragma unroll
    for (int off = 32; off > 0; off >>= 1)
        m = fmaxf(m, __shfl_down(m, off, 64));
    if ((t & 63) == 0) wred[t >> 6] = m;
    __syncthreads();
    if (t == 0)
        smax = fmaxf(fmaxf(wred[0], wred[1]), fmaxf(wred[2], wred[3]));
    __syncthreads();

    const float inv = 1.0f / smax;           // one IEEE divide
    const int idx = blockIdx.x * 256 + t;
    float4 v = out[idx];
    v.x *= inv; v.y *= inv; v.z *= inv; v.w *= inv;
    out[idx] = v;
}

extern "C" void kernel_launch(void* const* d_in, const int* in_sizes, int n_in,
                              void* d_out, int out_size, void* d_ws, size_t ws_size,
                              hipStream_t stream)
{
    const float* contour = (const float*)d_in[0];   // [2][2][64][2] fp32
    float* out = (float*)d_out;                     // [2][2][256][256] fp32
    float* ws  = (float*)d_ws;

    contour_prod_kernel<<<NBLK, SZ, 0, stream>>>(contour, out, ws);
    contour_norm_kernel<<<out_size / 4 / 256, 256, 0, stream>>>((float4*)out, ws);
}

// Round 8
// 21.941 us; speedup vs baseline: 1.1782x; 1.1782x over previous
//
#include <hip/hip_runtime.h>
#include <math.h>

#define SZ 256
#define KPTS 64
#define GROUPS 4
#define SEGS_PER (KPTS / GROUPS)   // 16 segments per thread
#define NBLK (4 * SZ * 2)          // 2048 prod blocks: bn(4) x i(256) x jq(2)
#define K_SIGN 100000.0f
#define EPS_C 1e-5f
#define INV_2PI 0.15915494309189535f
#define PI_F 3.14159265358979323846f
// 2*K_SIGN*log2(e): tanh(2K*c) = 1 - 2/(exp2(K2_LOG2E*c)+1)
#define K2_LOG2E 288539.00817779269f

__device__ __forceinline__ float fast_rcp(float x)  { return __builtin_amdgcn_rcpf(x); }
__device__ __forceinline__ float fast_sqrt(float x) { return __builtin_amdgcn_sqrtf(x); }
__device__ __forceinline__ float fast_rsq(float x)  { return __builtin_amdgcn_rsqf(x); }
__device__ __forceinline__ float fast_exp2(float x) { return __builtin_amdgcn_exp2f(x); }

// tanh(2K*cross) = 1 - 2/(exp2(K2_LOG2E*cross)+1); saturates cleanly.
__device__ __forceinline__ float fast_tanh_k(float cross) {
    float t = fast_exp2(K2_LOG2E * cross);
    return fmaf(-2.0f, fast_rcp(t + 1.0f), 1.0f);
}

// acos approx (Abramowitz-Stegun 4.4.45), max err ~6.7e-5 rad.
__device__ __forceinline__ float fast_acos(float x) {
    float ax = fabsf(x);
    float s  = fast_sqrt(1.0f - ax);
    float p  = s * fmaf(ax, fmaf(ax, fmaf(ax, -0.0187292994f, 0.0742610037f),
                                  -0.2121143937f), 1.5707288f);
    return (x >= 0.0f) ? p : (PI_F - p);
}

// d_ws: ws[blk] = per-block max, blk in [0,2048); fully rewritten every call.

// grid = 2048 blocks (bn*256*jq), block = 256 threads.
// thread t: g = t&3 (16-seg group), slot = t>>2 in [0,64) -> TWO pixels
// j0 = jq*128 + 2*slot, j1 = j0+1 (same row i => shared mx, shared dxn).
__global__ __launch_bounds__(256) void contour_prod_kernel(
    const float* __restrict__ contour,   // [4][64][2]
    float* __restrict__ out,             // [4][256][256] unnormalized
    float* __restrict__ ws)              // [2048] per-block maxes
{
    __shared__ float2 cpt[KPTS + 1];
    __shared__ float wred[4];

    const int blk = blockIdx.x;
    const int jq  = blk & 1;
    const int i   = (blk >> 1) & 255;
    const int bn  = blk >> 9;

    const int t = threadIdx.x;
    if (t < KPTS) {
        float2 p = ((const float2*)contour)[bn * KPTS + t];
        cpt[t] = p;
        if (t == 0) cpt[KPTS] = p;      // wraparound dup
    }
    __syncthreads();

    const int g    = t & 3;
    const int slot = t >> 2;
    const int j0   = (jq << 7) + (slot << 1);

    const float mx  = (float)i  * (1.0f / (float)SZ);
    const float my0 = (float)j0 * (1.0f / (float)SZ);
    const float my1 = my0 + (1.0f / (float)SZ);

    const int base = g * SEGS_PER;

    float2 cp = cpt[base];
    float dxc  = cp.x - mx;
    float dyc0 = cp.y - my0;
    float dyc1 = cp.y - my1;
    const float dx2c = dxc * dxc;
    float n2c0 = fmaf(dyc0, dyc0, dx2c);
    float n2c1 = fmaf(dyc1, dyc1, dx2c);
    float mn0  = n2c0, mn1 = n2c1;      // min squared norms
    float acc0 = 0.0f, acc1 = 0.0f;

    #pragma unroll
    for (int kk = 0; kk < SEGS_PER; ++kk) {
        const float2 cn = cpt[base + kk + 1];
        const float dxn  = cn.x - mx;            // shared between pixels
        const float dyn0 = cn.y - my0;
        const float dyn1 = cn.y - my1;
        const float dx2  = dxn * dxn;            // shared
        const float n2n0 = fmaf(dyn0, dyn0, dx2);
        const float n2n1 = fmaf(dyn1, dyn1, dx2);
        mn0 = fminf(mn0, n2n0);
        mn1 = fminf(mn1, n2n1);

        const float dd = dxc * dxn;              // shared
        const float cross0 = fmaf(dyc0, dxn, -dxc * dyn0);
        const float cross1 = fmaf(dyc1, dxn, -dxc * dyn1);
        const float dot0   = fmaf(dyc0, dyn0, dd);
        const float dot1   = fmaf(dyc1, dyn1, dd);

        float ca0 = dot0 * fast_rsq(n2c0 * n2n0);
        float ca1 = dot1 * fast_rsq(n2c1 * n2n1);
        ca0 = fminf(fmaxf(ca0, -1.0f + EPS_C), 1.0f - EPS_C);   // v_med3
        ca1 = fminf(fmaxf(ca1, -1.0f + EPS_C), 1.0f - EPS_C);
        const float ang0 = fast_acos(ca0);
        const float ang1 = fast_acos(ca1);

        const float s0 = fast_tanh_k(cross0);
        const float s1 = fast_tanh_k(cross1);

        acc0 = fmaf(s0, ang0, acc0);
        acc1 = fmaf(s1, ang1, acc1);

        dxc = dxn;
        dyc0 = dyn0; dyc1 = dyn1;
        n2c0 = n2n0; n2c1 = n2n1;
    }

    // combine 4 segment-groups per pixel (4-lane butterflies)
    acc0 += __shfl_xor(acc0, 1, 64);
    acc0 += __shfl_xor(acc0, 2, 64);
    acc1 += __shfl_xor(acc1, 1, 64);
    acc1 += __shfl_xor(acc1, 2, 64);
    mn0 = fminf(mn0, __shfl_xor(mn0, 1, 64));
    mn0 = fminf(mn0, __shfl_xor(mn0, 2, 64));
    mn1 = fminf(mn1, __shfl_xor(mn1, 1, 64));
    mn1 = fminf(mn1, __shfl_xor(mn1, 2, 64));

    const float prod0 = fabsf(acc0) * INV_2PI * fast_sqrt(mn0);
    const float prod1 = fabsf(acc1) * INV_2PI * fast_sqrt(mn1);
    if (g == 0) {
        float2 pv = make_float2(prod0, prod1);
        ((float2*)out)[(((bn << 8) + i) << 7) + (jq << 6) + slot] = pv;
    }

    // block max -> plain store
    float wmax = fmaxf(prod0, prod1);
    #pragma unroll
    for (int off = 32; off > 0; off >>= 1)
        wmax = fmaxf(wmax, __shfl_down(wmax, off, 64));
    if ((t & 63) == 0) wred[t >> 6] = wmax;
    __syncthreads();
    if (t == 0)
        ws[blk] = fmaxf(fmaxf(wred[0], wred[1]), fmaxf(wred[2], wred[3]));
}

// 256 blocks x 256 threads. Each block re-reduces ws[0..2047] (8 KB, L2-hit),
// then normalizes its 1024-pixel chunk (float4 per thread).
__global__ __launch_bounds__(256) void contour_norm_kernel(
    float4* __restrict__ out,
    const float* __restrict__ ws)
{
    __shared__ float wred[4];
    __shared__ float smax;

    const int t = threadIdx.x;
    const float4* w4 = (const float4*)ws;   // 512 float4

    float m = 0.0f;                          // prod >= 0
    {
        float4 a = w4[t];
        float4 b = w4[t + 256];
        m = fmaxf(fmaxf(fmaxf(a.x, a.y), fmaxf(a.z, a.w)),
                  fmaxf(fmaxf(b.x, b.y), fmaxf(b.z, b.w)));
    }
    #pragma unroll
    for (int off = 32; off > 0; off >>= 1)
        m = fmaxf(m, __shfl_down(m, off, 64));
    if ((t & 63) == 0) wred[t >> 6] = m;
    __syncthreads();
    if (t == 0)
        smax = fmaxf(fmaxf(wred[0], wred[1]), fmaxf(wred[2], wred[3]));
    __syncthreads();

    const float inv = 1.0f / smax;           // one IEEE divide
    const int idx = blockIdx.x * 256 + t;
    float4 v = out[idx];
    v.x *= inv; v.y *= inv; v.z *= inv; v.w *= inv;
    out[idx] = v;
}

extern "C" void kernel_launch(void* const* d_in, const int* in_sizes, int n_in,
                              void* d_out, int out_size, void* d_ws, size_t ws_size,
                              hipStream_t stream)
{
    const float* contour = (const float*)d_in[0];   // [2][2][64][2] fp32
    float* out = (float*)d_out;                     // [2][2][256][256] fp32
    float* ws  = (float*)d_ws;

    contour_prod_kernel<<<NBLK, SZ, 0, stream>>>(contour, out, ws);
    contour_norm_kernel<<<out_size / 4 / 256, 256, 0, stream>>>((float4*)out, ws);
}